// Round 11
// baseline (804.343 us; speedup 1.0000x reference)
//
#include <hip/hip_runtime.h>
#include <hip/hip_bf16.h>
#include <stdint.h>

// dMaSIFConv — R11 (= R10 with the cvt_pkrtz return-type fixed via bit_cast).
// R9 evidence: D lived in AGPRs with per-chunk zero-remat + accvgpr moves,
// pinned by sched_barrier(0) -> 1334 VALU-cyc/wave-chunk vs ~520 ideal.
// Changes vs R9: no sched_barrier, zero-C hoisted out of the K-loop,
// cvt_pkrtz packing. Verified MFMA layouts and staging untouched.
// N=8192, I=16, H=O=64, CUTS=8, GROUPS=4. Wire dtype bf16 (detect kept).

#define N_PTS   8192
#define CHUNK   64
#define NCHUNK  (N_PTS / CHUNK)
#define WPB     8                       // waves per conv block
#define PSCALE  0.07856742013183861f    // 1/(sqrt(2)*9)
#define GN_CNT  (N_PTS * 16)

// fp32 pool offsets (prefix sums of input element counts)
#define OFF_POINTS 0
#define OFF_NUV    24576
#define OFF_FEAT   98304
#define OFF_WIN1   229376
#define OFF_BIN1   230400
#define OFF_WIN2   230464
#define OFF_BIN2   234560
#define OFF_GNIW   234624
#define OFF_GNIB   234688
#define OFF_A1     234752
#define OFF_B1     234776
#define OFF_A2     234784
#define OFF_B2     235296
#define OFF_WOUT1  235360
#define OFF_BOUT1  239456
#define OFF_WOUT2  239520
#define OFF_BOUT2  243616
#define OFF_GNOW   243680
#define OFF_GNOB   243744
#define CVT_TOTAL  243808
#define NSEG 19

typedef _Float16 half2_t __attribute__((ext_vector_type(2)));
typedef _Float16 f16x8   __attribute__((ext_vector_type(8)));
typedef float    f32x16  __attribute__((ext_vector_type(16)));

struct InPtrs { const void* p[NSEG]; };

__device__ __forceinline__ float rfl(float x) {
  return __int_as_float(__builtin_amdgcn_readfirstlane(__float_as_int(x)));
}
__device__ __forceinline__ float leaky(float x) { return x > 0.f ? x : 0.2f * x; }

#if __has_builtin(__builtin_amdgcn_cvt_pkrtz)
__device__ __forceinline__ half2_t pk16(float a, float b) {
  return __builtin_bit_cast(half2_t, __builtin_amdgcn_cvt_pkrtz(a, b));
}
#else
__device__ __forceinline__ half2_t pk16(float a, float b) {
  half2_t r; r.x = (_Float16)a; r.y = (_Float16)b; return r;
}
#endif

// ---------------- prep: detect dtype, convert all inputs to fp32 pool -------
__global__ __launch_bounds__(256) void prep_kernel(InPtrs ptrs, float* dst,
                                                   float* gstats) {
  if (blockIdx.x == 0 && threadIdx.x < 16) gstats[threadIdx.x] = 0.f;
  const uint32_t w0 = ((const uint32_t*)ptrs.p[7])[0];   // gn_in_w (all ones)
  const bool bf = (w0 != 0x3F800000u);
  const int CUM[NSEG + 1] = {0, 24576, 98304, 229376, 230400, 230464, 234560,
                             234624, 234688, 234752, 234776, 234784, 235296,
                             235360, 239456, 239520, 243616, 243680, 243744,
                             243808};
  for (int e = blockIdx.x * 256 + threadIdx.x; e < CVT_TOTAL;
       e += gridDim.x * 256) {
    int s = 0;
#pragma unroll
    for (int i = 1; i < NSEG; ++i) s += (e >= CUM[i]) ? 1 : 0;
    const int rem = e - CUM[s];
    float v = bf ? __bfloat162float(((const __hip_bfloat16*)ptrs.p[s])[rem])
                 : ((const float*)ptrs.p[s])[rem];
    if (s == 0) v *= PSCALE;
    dst[e] = v;
  }
}

// ---------------- input MLP (fp32 pool, float4 loads) -----------------------
__global__ __launch_bounds__(256) void mlp_in_kernel(
    const float* __restrict__ pool, float* __restrict__ fbuf) {
  __shared__ float ls[4][64];
  const int t = threadIdx.x, nl = t >> 6, h = t & 63;
  const int n = blockIdx.x * 4 + nl;
  const float4* fr = (const float4*)(pool + OFF_FEAT + n * 16);
  const float4* w1 = (const float4*)(pool + OFF_WIN1 + h * 16);
  float a = pool[OFF_BIN1 + h];
#pragma unroll
  for (int k = 0; k < 4; ++k) {
    const float4 x = fr[k], w = w1[k];
    a = fmaf(x.x, w.x, a); a = fmaf(x.y, w.y, a);
    a = fmaf(x.z, w.z, a); a = fmaf(x.w, w.w, a);
  }
  ls[nl][h] = leaky(a);
  __syncthreads();
  const float4* w2 = (const float4*)(pool + OFF_WIN2 + h * 64);
  const float4* lr = (const float4*)&ls[nl][0];
  float c = pool[OFF_BIN2 + h];
#pragma unroll
  for (int k = 0; k < 16; ++k) {
    const float4 x = lr[k], w = w2[k];
    c = fmaf(x.x, w.x, c); c = fmaf(x.y, w.y, c);
    c = fmaf(x.z, w.z, c); c = fmaf(x.w, w.w, c);
  }
  fbuf[n * 64 + h] = leaky(c);
}

// ---------------- output MLP (fp32 cbuf input) ------------------------------
__global__ __launch_bounds__(256) void mlp_out_kernel(
    const float* __restrict__ cbuf, const float* __restrict__ pool,
    float* __restrict__ obuf) {
  __shared__ float ls[4][64];
  const int t = threadIdx.x, nl = t >> 6, h = t & 63;
  const int n = blockIdx.x * 4 + nl;
  const float4* cr = (const float4*)(cbuf + n * 64);
  const float4* w1 = (const float4*)(pool + OFF_WOUT1 + h * 64);
  float a = pool[OFF_BOUT1 + h];
#pragma unroll
  for (int k = 0; k < 16; ++k) {
    const float4 x = cr[k], w = w1[k];
    a = fmaf(x.x, w.x, a); a = fmaf(x.y, w.y, a);
    a = fmaf(x.z, w.z, a); a = fmaf(x.w, w.w, a);
  }
  ls[nl][h] = leaky(a);
  __syncthreads();
  const float4* w2 = (const float4*)(pool + OFF_WOUT2 + h * 64);
  const float4* lr = (const float4*)&ls[nl][0];
  float c = pool[OFF_BOUT2 + h];
#pragma unroll
  for (int k = 0; k < 16; ++k) {
    const float4 x = lr[k], w = w2[k];
    c = fmaf(x.x, w.x, c); c = fmaf(x.y, w.y, c);
    c = fmaf(x.z, w.z, c); c = fmaf(x.w, w.w, c);
  }
  obuf[n * 64 + h] = leaky(c);
}

// ---------------- GN stats: 64 blocks, LDS + global atomics -----------------
__global__ __launch_bounds__(256) void gn_stats_kernel(
    const float* __restrict__ buf, float* __restrict__ gstats) {
  __shared__ float red[8];
  const int t = threadIdx.x;
  const int g = (t & 63) >> 4;
  if (t < 8) red[t] = 0.f;
  float s = 0.f, q = 0.f;
  for (int idx = blockIdx.x * 256 + t; idx < N_PTS * 64; idx += 64 * 256) {
    const float v = buf[idx];
    s += v; q = fmaf(v, v, q);
  }
  __syncthreads();
  atomicAdd(&red[g], s);
  atomicAdd(&red[4 + g], q);
  __syncthreads();
  if (t < 8) atomicAdd(&gstats[t], red[t]);
}

// ---------------- GN apply (in-place fp32) ----------------------------------
__global__ __launch_bounds__(256) void gn_apply_kernel(
    float* __restrict__ buf, const float* __restrict__ gstats,
    const float* __restrict__ pool) {
  const int idx = blockIdx.x * 256 + threadIdx.x;
  const int h = idx & 63, g = h >> 4;
  const float m = gstats[g] * (1.f / GN_CNT);
  const float v = gstats[4 + g] * (1.f / GN_CNT) - m * m;
  const float rs = rsqrtf(fmaxf(v, 0.f) + 1e-5f);
  buf[idx] = fmaf((buf[idx] - m) * rs, pool[OFF_GNIW + h], pool[OFF_GNIB + h]);
}

// ---------------- GN apply + final store (dtype-branched) -------------------
__global__ __launch_bounds__(256) void gn_apply_out_kernel(
    const float* __restrict__ buf, const float* __restrict__ gstats,
    const float* __restrict__ pool, void* __restrict__ out,
    const uint32_t* __restrict__ dref) {
  const bool bf = (dref[0] != 0x3F800000u);
  const int idx = blockIdx.x * 256 + threadIdx.x;
  const int h = idx & 63, g = h >> 4;
  const float m = gstats[g] * (1.f / GN_CNT);
  const float v = gstats[4 + g] * (1.f / GN_CNT) - m * m;
  const float rs = rsqrtf(fmaxf(v, 0.f) + 1e-5f);
  const float r = fmaf((buf[idx] - m) * rs, pool[OFF_GNOW + h], pool[OFF_GNOB + h]);
  if (bf) ((__hip_bfloat16*)out)[idx] = __float2bfloat16(r);
  else    ((float*)out)[idx] = r;
}

// ---------------- O(N^2) conv, MFMA phase-2 ---------------------------------
// 8 waves/block, 1024 blocks, no min-waves clause (allocator free, no spill).
// phase 1: lane j computes w_j, hc'[c]=w*relu(hc) (f16, cvt_pkrtz) and stages
//   the MFMA A-fragment (k0..7 b128; k8 word = w; k9..15 pre-zeroed once).
// phase 2: 4 tiles (jt,ht): MFMA 32x32x16_f16 (zero-C hoisted) + 16x
//   {ds_read_b32 f + max + fma}; scheduler free to interleave tiles.
__global__ __launch_bounds__(512) void conv_kernel(
    const float* __restrict__ pool, const float* __restrict__ fbuf,
    float* __restrict__ cbuf) {
  __shared__ float  f_s[CHUNK * 64];     // 16 KB f-tile (shared by 8 waves)
  __shared__ float4 hcA[WPB][2][64];     // 16 KB per-wave A-fragments

  const int t = threadIdx.x;
  const int wv = t >> 6, lane = t & 63;
  const int b = blockIdx.x * WPB + wv;
  const int half = lane >> 5;            // k-group: 0 -> k 0..7, 1 -> k 8..15
  const int l31 = lane & 31;

  // wave-uniform query data -> SGPRs
  const float pbx = rfl(pool[OFF_POINTS + b * 3 + 0]);
  const float pby = rfl(pool[OFF_POINTS + b * 3 + 1]);
  const float pbz = rfl(pool[OFF_POINTS + b * 3 + 2]);
  float nb[9];
#pragma unroll
  for (int i = 0; i < 9; ++i) nb[i] = rfl(pool[OFF_NUV + b * 9 + i]);
  float a1v[24], b1v[8];
#pragma unroll
  for (int i = 0; i < 24; ++i) a1v[i] = rfl(pool[OFF_A1 + i]);
#pragma unroll
  for (int i = 0; i < 8; ++i)  b1v[i] = rfl(pool[OFF_B1 + i]);

  // constant B fragments: B[k][h] = A2[h][k] (k<8), B2[h] (k==8), 0 (k>8).
  f16x8 bfrag[2];
#pragma unroll
  for (int ht = 0; ht < 2; ++ht) {
    const int h = l31 + 32 * ht;
#pragma unroll
    for (int i = 0; i < 8; ++i) {
      const float v = (half == 0) ? pool[OFF_A2 + h * 8 + i]
                                  : ((i == 0) ? pool[OFF_B2 + h] : 0.f);
      bfrag[ht][i] = (_Float16)v;
    }
  }

  // pre-zero the k8..15 half of this wave's A-fragment rows (only the k8
  // word changes per chunk; k9..15 stay zero for the whole kernel)
  {
    float4 z4; z4.x = 0.f; z4.y = 0.f; z4.z = 0.f; z4.w = 0.f;
    hcA[wv][half][l31 + 32] = z4;
  }

  // hoisted zero-C accumulator (paid once, not per chunk)
  const f32x16 kzero = {0.f, 0.f, 0.f, 0.f, 0.f, 0.f, 0.f, 0.f,
                        0.f, 0.f, 0.f, 0.f, 0.f, 0.f, 0.f, 0.f};

  float acc0 = 0.f, acc1 = 0.f;
  const float4* fg4 = (const float4*)fbuf;

  for (int c = 0; c < NCHUNK; ++c) {
    // stage f chunk (4096 floats): 512 threads x 2 float4
    const float4 fv0 = fg4[c * 1024 + t];
    const float4 fv1 = fg4[c * 1024 + t + 512];
    // phase-1 inputs for this lane's n
    const int n = c * CHUNK + lane;
    const float px = pool[OFF_POINTS + n * 3 + 0];
    const float py = pool[OFF_POINTS + n * 3 + 1];
    const float pz = pool[OFF_POINTS + n * 3 + 2];
    const float nx = pool[OFF_NUV + n * 9 + 0];
    const float ny = pool[OFF_NUV + n * 9 + 1];
    const float nz = pool[OFF_NUV + n * 9 + 2];

    __syncthreads();                     // prior chunk's LDS reads done
    ((float4*)f_s)[t]       = fv0;
    ((float4*)f_s)[t + 512] = fv1;

    // phase 1: row j = lane of Hc' = [w*relu(hc)[0..7], w, 0...]
    const float dx = px - pbx, dy = py - pby, dz = pz - pbz;
    const float X0 = fmaf(nb[0], dx, fmaf(nb[1], dy, nb[2] * dz));
    const float X1 = fmaf(nb[3], dx, fmaf(nb[4], dy, nb[5] * dz));
    const float X2 = fmaf(nb[6], dx, fmaf(nb[7], dy, nb[8] * dz));
    const float dn = fmaf(nb[0], nx, fmaf(nb[1], ny, nb[2] * nz));
    const float dd = fmaf(dx, dx, fmaf(dy, dy, dz * dz));
    const float tt = 2.f - dn;
    const float w = __expf(-dd * tt * tt);

    float hc[8];
#pragma unroll
    for (int cc = 0; cc < 8; ++cc)
      hc[cc] = w * fmaxf(fmaf(X0, a1v[cc * 3 + 0],
                         fmaf(X1, a1v[cc * 3 + 1],
                         fmaf(X2, a1v[cc * 3 + 2], b1v[cc]))), 0.f);
    float4 lo;
    lo.x = __builtin_bit_cast(float, pk16(hc[0], hc[1]));
    lo.y = __builtin_bit_cast(float, pk16(hc[2], hc[3]));
    lo.z = __builtin_bit_cast(float, pk16(hc[4], hc[5]));
    lo.w = __builtin_bit_cast(float, pk16(hc[6], hc[7]));
    // A-frag staging: lane L of tile jt reads row (L&31)+32jt, k 8*(L>>5)+i
    hcA[wv][lane >> 5][l31] = lo;                       // k 0..7 of row lane
    ((float*)&hcA[wv][lane >> 5][l31 + 32])[0] =
        __builtin_bit_cast(float, pk16(w, 0.f));        // k 8 word (w)

    __syncthreads();                     // f_s + hcA visible

    // phase 2: 2 jt-tiles x 2 ht-tiles
#pragma unroll
    for (int jt = 0; jt < 2; ++jt) {
      const float4 av = hcA[wv][jt][lane];              // ds_read_b128
      const f16x8 af = __builtin_bit_cast(f16x8, av);
      const int fbase = (32 * jt + 4 * half) * 64 + l31;
#pragma unroll
      for (int ht = 0; ht < 2; ++ht) {
        const f32x16 D = __builtin_amdgcn_mfma_f32_32x32x16_f16(
            af, bfrag[ht], kzero, 0, 0, 0);
        const float* fb = &f_s[fbase + 32 * ht];
        float a = (ht == 0) ? acc0 : acc1;
#pragma unroll
        for (int r = 0; r < 16; ++r) {
          const float fj = fb[((r & 3) + 8 * (r >> 2)) * 64];
          a = fmaf(fj, fmaxf(D[r], 0.f), a);
        }
        if (ht == 0) acc0 = a; else acc1 = a;
      }
    }
  }

  // each col's sum is split across lane pairs (L, L^32): combine
  acc0 += __shfl_xor(acc0, 32, 64);
  acc1 += __shfl_xor(acc1, 32, 64);
  if (lane < 32) {
    cbuf[b * 64 + l31]      = acc0;
    cbuf[b * 64 + l31 + 32] = acc1;
  }
}

extern "C" void kernel_launch(void* const* d_in, const int* in_sizes, int n_in,
                              void* d_out, int out_size, void* d_ws, size_t ws_size,
                              hipStream_t stream) {
  (void)in_sizes; (void)n_in; (void)out_size; (void)ws_size;
  const uint32_t* dref = (const uint32_t*)d_in[7];   // gn_in_w, all-ones

  float* pool   = (float*)d_ws;               // CVT_TOTAL fp32 inputs
  float* fbuf   = pool + CVT_TOTAL;           // N*64
  float* cbuf   = fbuf + N_PTS * 64;          // N*64
  float* gstats = cbuf + N_PTS * 64;          // 16 (in:0-7, out:8-15)

  InPtrs ptrs;
  for (int i = 0; i < NSEG; ++i) ptrs.p[i] = d_in[i];

  prep_kernel<<<256, 256, 0, stream>>>(ptrs, pool, gstats);
  mlp_in_kernel<<<N_PTS / 4, 256, 0, stream>>>(pool, fbuf);
  gn_stats_kernel<<<64, 256, 0, stream>>>(fbuf, gstats);
  gn_apply_kernel<<<N_PTS * 64 / 256, 256, 0, stream>>>(fbuf, gstats, pool);
  conv_kernel<<<N_PTS / WPB, 512, 0, stream>>>(pool, fbuf, cbuf);
  mlp_out_kernel<<<N_PTS / 4, 256, 0, stream>>>(cbuf, pool, fbuf);
  gn_stats_kernel<<<64, 256, 0, stream>>>(fbuf, gstats + 8);
  gn_apply_out_kernel<<<N_PTS * 64 / 256, 256, 0, stream>>>(
      fbuf, gstats + 8, pool, d_out, dref);
}

// Round 12
// 699.206 us; speedup vs baseline: 1.1504x; 1.1504x over previous
//
#include <hip/hip_runtime.h>
#include <hip/hip_bf16.h>
#include <stdint.h>

// dMaSIFConv — R12: conv phase-2 on 16x16x32 f16 MFMA (D = 4 regs, not 16).
// R11 evidence: 32x32 tiles -> 16-reg D + 16-reg kzero in flight -> >128
// regs/wave -> 2 waves/SIMD (occupancy 24%) -> VALUBusy 64%. Same math on
// 16x16 tiles cuts acc pressure 4x; VALU count unchanged; matrix pipe (8%
// util) absorbs the extra MFMA issues. f_s rows padded to 68 floats so the
// 4-row C/D grouping stays 2-way in LDS banks (free per m136).
// N=8192, I=16, H=O=64, CUTS=8, GROUPS=4. Wire dtype bf16 (detect kept).

#define N_PTS   8192
#define CHUNK   64
#define NCHUNK  (N_PTS / CHUNK)
#define WPB     8                       // waves per conv block
#define PSCALE  0.07856742013183861f    // 1/(sqrt(2)*9)
#define GN_CNT  (N_PTS * 16)
#define FS_STRIDE 68                    // padded f_s row stride (floats)

// fp32 pool offsets (prefix sums of input element counts)
#define OFF_POINTS 0
#define OFF_NUV    24576
#define OFF_FEAT   98304
#define OFF_WIN1   229376
#define OFF_BIN1   230400
#define OFF_WIN2   230464
#define OFF_BIN2   234560
#define OFF_GNIW   234624
#define OFF_GNIB   234688
#define OFF_A1     234752
#define OFF_B1     234776
#define OFF_A2     234784
#define OFF_B2     235296
#define OFF_WOUT1  235360
#define OFF_BOUT1  239456
#define OFF_WOUT2  239520
#define OFF_BOUT2  243616
#define OFF_GNOW   243680
#define OFF_GNOB   243744
#define CVT_TOTAL  243808
#define NSEG 19

typedef _Float16 half2_t __attribute__((ext_vector_type(2)));
typedef _Float16 f16x8   __attribute__((ext_vector_type(8)));
typedef float    f32x4   __attribute__((ext_vector_type(4)));

struct InPtrs { const void* p[NSEG]; };

__device__ __forceinline__ float rfl(float x) {
  return __int_as_float(__builtin_amdgcn_readfirstlane(__float_as_int(x)));
}
__device__ __forceinline__ float leaky(float x) { return x > 0.f ? x : 0.2f * x; }

#if __has_builtin(__builtin_amdgcn_cvt_pkrtz)
__device__ __forceinline__ half2_t pk16(float a, float b) {
  return __builtin_bit_cast(half2_t, __builtin_amdgcn_cvt_pkrtz(a, b));
}
#else
__device__ __forceinline__ half2_t pk16(float a, float b) {
  half2_t r; r.x = (_Float16)a; r.y = (_Float16)b; return r;
}
#endif

// ---------------- prep: detect dtype, convert all inputs to fp32 pool -------
__global__ __launch_bounds__(256) void prep_kernel(InPtrs ptrs, float* dst,
                                                   float* gstats) {
  if (blockIdx.x == 0 && threadIdx.x < 16) gstats[threadIdx.x] = 0.f;
  const uint32_t w0 = ((const uint32_t*)ptrs.p[7])[0];   // gn_in_w (all ones)
  const bool bf = (w0 != 0x3F800000u);
  const int CUM[NSEG + 1] = {0, 24576, 98304, 229376, 230400, 230464, 234560,
                             234624, 234688, 234752, 234776, 234784, 235296,
                             235360, 239456, 239520, 243616, 243680, 243744,
                             243808};
  for (int e = blockIdx.x * 256 + threadIdx.x; e < CVT_TOTAL;
       e += gridDim.x * 256) {
    int s = 0;
#pragma unroll
    for (int i = 1; i < NSEG; ++i) s += (e >= CUM[i]) ? 1 : 0;
    const int rem = e - CUM[s];
    float v = bf ? __bfloat162float(((const __hip_bfloat16*)ptrs.p[s])[rem])
                 : ((const float*)ptrs.p[s])[rem];
    if (s == 0) v *= PSCALE;
    dst[e] = v;
  }
}

// ---------------- input MLP (fp32 pool, float4 loads) -----------------------
__global__ __launch_bounds__(256) void mlp_in_kernel(
    const float* __restrict__ pool, float* __restrict__ fbuf) {
  __shared__ float ls[4][64];
  const int t = threadIdx.x, nl = t >> 6, h = t & 63;
  const int n = blockIdx.x * 4 + nl;
  const float4* fr = (const float4*)(pool + OFF_FEAT + n * 16);
  const float4* w1 = (const float4*)(pool + OFF_WIN1 + h * 16);
  float a = pool[OFF_BIN1 + h];
#pragma unroll
  for (int k = 0; k < 4; ++k) {
    const float4 x = fr[k], w = w1[k];
    a = fmaf(x.x, w.x, a); a = fmaf(x.y, w.y, a);
    a = fmaf(x.z, w.z, a); a = fmaf(x.w, w.w, a);
  }
  ls[nl][h] = leaky(a);
  __syncthreads();
  const float4* w2 = (const float4*)(pool + OFF_WIN2 + h * 64);
  const float4* lr = (const float4*)&ls[nl][0];
  float c = pool[OFF_BIN2 + h];
#pragma unroll
  for (int k = 0; k < 16; ++k) {
    const float4 x = lr[k], w = w2[k];
    c = fmaf(x.x, w.x, c); c = fmaf(x.y, w.y, c);
    c = fmaf(x.z, w.z, c); c = fmaf(x.w, w.w, c);
  }
  fbuf[n * 64 + h] = leaky(c);
}

// ---------------- output MLP (fp32 cbuf input) ------------------------------
__global__ __launch_bounds__(256) void mlp_out_kernel(
    const float* __restrict__ cbuf, const float* __restrict__ pool,
    float* __restrict__ obuf) {
  __shared__ float ls[4][64];
  const int t = threadIdx.x, nl = t >> 6, h = t & 63;
  const int n = blockIdx.x * 4 + nl;
  const float4* cr = (const float4*)(cbuf + n * 64);
  const float4* w1 = (const float4*)(pool + OFF_WOUT1 + h * 64);
  float a = pool[OFF_BOUT1 + h];
#pragma unroll
  for (int k = 0; k < 16; ++k) {
    const float4 x = cr[k], w = w1[k];
    a = fmaf(x.x, w.x, a); a = fmaf(x.y, w.y, a);
    a = fmaf(x.z, w.z, a); a = fmaf(x.w, w.w, a);
  }
  ls[nl][h] = leaky(a);
  __syncthreads();
  const float4* w2 = (const float4*)(pool + OFF_WOUT2 + h * 64);
  const float4* lr = (const float4*)&ls[nl][0];
  float c = pool[OFF_BOUT2 + h];
#pragma unroll
  for (int k = 0; k < 16; ++k) {
    const float4 x = lr[k], w = w2[k];
    c = fmaf(x.x, w.x, c); c = fmaf(x.y, w.y, c);
    c = fmaf(x.z, w.z, c); c = fmaf(x.w, w.w, c);
  }
  obuf[n * 64 + h] = leaky(c);
}

// ---------------- GN stats: 64 blocks, LDS + global atomics -----------------
__global__ __launch_bounds__(256) void gn_stats_kernel(
    const float* __restrict__ buf, float* __restrict__ gstats) {
  __shared__ float red[8];
  const int t = threadIdx.x;
  const int g = (t & 63) >> 4;
  if (t < 8) red[t] = 0.f;
  float s = 0.f, q = 0.f;
  for (int idx = blockIdx.x * 256 + t; idx < N_PTS * 64; idx += 64 * 256) {
    const float v = buf[idx];
    s += v; q = fmaf(v, v, q);
  }
  __syncthreads();
  atomicAdd(&red[g], s);
  atomicAdd(&red[4 + g], q);
  __syncthreads();
  if (t < 8) atomicAdd(&gstats[t], red[t]);
}

// ---------------- GN apply (in-place fp32) ----------------------------------
__global__ __launch_bounds__(256) void gn_apply_kernel(
    float* __restrict__ buf, const float* __restrict__ gstats,
    const float* __restrict__ pool) {
  const int idx = blockIdx.x * 256 + threadIdx.x;
  const int h = idx & 63, g = h >> 4;
  const float m = gstats[g] * (1.f / GN_CNT);
  const float v = gstats[4 + g] * (1.f / GN_CNT) - m * m;
  const float rs = rsqrtf(fmaxf(v, 0.f) + 1e-5f);
  buf[idx] = fmaf((buf[idx] - m) * rs, pool[OFF_GNIW + h], pool[OFF_GNIB + h]);
}

// ---------------- GN apply + final store (dtype-branched) -------------------
__global__ __launch_bounds__(256) void gn_apply_out_kernel(
    const float* __restrict__ buf, const float* __restrict__ gstats,
    const float* __restrict__ pool, void* __restrict__ out,
    const uint32_t* __restrict__ dref) {
  const bool bf = (dref[0] != 0x3F800000u);
  const int idx = blockIdx.x * 256 + threadIdx.x;
  const int h = idx & 63, g = h >> 4;
  const float m = gstats[g] * (1.f / GN_CNT);
  const float v = gstats[4 + g] * (1.f / GN_CNT) - m * m;
  const float rs = rsqrtf(fmaxf(v, 0.f) + 1e-5f);
  const float r = fmaf((buf[idx] - m) * rs, pool[OFF_GNOW + h], pool[OFF_GNOB + h]);
  if (bf) ((__hip_bfloat16*)out)[idx] = __float2bfloat16(r);
  else    ((float*)out)[idx] = r;
}

// ---------------- O(N^2) conv, 16x16x32 MFMA phase-2 ------------------------
// 8 waves/block, 1024 blocks. Per 64-n chunk:
// phase 1: lane j computes w_j, hc'[c]=w*relu(hc) -> f16 A-fragment rows in
//   per-wave LDS (kg0 entry b128; kg1 word0 = w; rest pre-zeroed once).
// phase 2: 4 jt x 4 ht tiles of mfma_f32_16x16x32_f16 (K used: 0..8).
//   A[m=lane&15][k=8*(lane>>4)+i]; kg>=2 lanes read a shared zero float4.
//   C/D: col=lane&15, row=(lane>>4)*4+r. Epilogue: 4x {ds_read f + max+fma}.
// Final: acc[ht] reduced over lane quads (xor 16,32), lanes 0..15 store.
__global__ __launch_bounds__(512) void conv_kernel(
    const float* __restrict__ pool, const float* __restrict__ fbuf,
    float* __restrict__ cbuf) {
  __shared__ float  f_s[CHUNK * FS_STRIDE];  // 17408 B padded f-tile
  __shared__ float4 hcA[WPB][4][32];         // 16 KB per-wave A-fragments
  __shared__ float4 zero4_s;                 // broadcast source for kg>=2

  const int t = threadIdx.x;
  const int wv = t >> 6, lane = t & 63;
  const int b = blockIdx.x * WPB + wv;
  const int kg  = lane >> 4;                 // k-group: k = 8*kg + i
  const int l15 = lane & 15;

  // wave-uniform query data -> SGPRs
  const float pbx = rfl(pool[OFF_POINTS + b * 3 + 0]);
  const float pby = rfl(pool[OFF_POINTS + b * 3 + 1]);
  const float pbz = rfl(pool[OFF_POINTS + b * 3 + 2]);
  float nb[9];
#pragma unroll
  for (int i = 0; i < 9; ++i) nb[i] = rfl(pool[OFF_NUV + b * 9 + i]);
  float a1v[24], b1v[8];
#pragma unroll
  for (int i = 0; i < 24; ++i) a1v[i] = rfl(pool[OFF_A1 + i]);
#pragma unroll
  for (int i = 0; i < 8; ++i)  b1v[i] = rfl(pool[OFF_B1 + i]);

  // B fragments: B[k][h] = A2[h][k] (k<8), B2[h] (k==8), 0 (k>8).
  // lane holds col h = 16*ht + l15, k = 8*kg + i.
  f16x8 bfrag[4];
#pragma unroll
  for (int ht = 0; ht < 4; ++ht) {
    const int h = 16 * ht + l15;
#pragma unroll
    for (int i = 0; i < 8; ++i) {
      float v = 0.f;
      if (kg == 0) v = pool[OFF_A2 + h * 8 + i];
      else if (kg == 1 && i == 0) v = pool[OFF_B2 + h];
      bfrag[ht][i] = (_Float16)v;
    }
  }

  // pre-zero hcA (kg1 words 1..3 + safety) and the shared zero float4
  {
    float4 z4; z4.x = 0.f; z4.y = 0.f; z4.z = 0.f; z4.w = 0.f;
    if (lane < 32) {
#pragma unroll
      for (int jt = 0; jt < 4; ++jt) hcA[wv][jt][lane] = z4;
    }
    if (t == 0) zero4_s = z4;
  }

  const f32x4 kzero = {0.f, 0.f, 0.f, 0.f};
  float acc[4] = {0.f, 0.f, 0.f, 0.f};
  const float4* fg4 = (const float4*)fbuf;

  for (int c = 0; c < NCHUNK; ++c) {
    // stage f chunk: 512 threads x 2 float4 into the 68-stride tile
    const float4 fv0 = fg4[c * 1024 + t];
    const float4 fv1 = fg4[c * 1024 + t + 512];
    // phase-1 inputs for this lane's n
    const int n = c * CHUNK + lane;
    const float px = pool[OFF_POINTS + n * 3 + 0];
    const float py = pool[OFF_POINTS + n * 3 + 1];
    const float pz = pool[OFF_POINTS + n * 3 + 2];
    const float nx = pool[OFF_NUV + n * 9 + 0];
    const float ny = pool[OFF_NUV + n * 9 + 1];
    const float nz = pool[OFF_NUV + n * 9 + 2];

    __syncthreads();                     // prior chunk's LDS reads done
    ((float4*)f_s)[(t >> 4) * 17 + (t & 15)]        = fv0;   // rows 0..31
    ((float4*)f_s)[((t >> 4) + 32) * 17 + (t & 15)] = fv1;   // rows 32..63

    // phase 1: row j = lane of Hc' = [w*relu(hc)[0..7], w, 0...]
    const float dx = px - pbx, dy = py - pby, dz = pz - pbz;
    const float X0 = fmaf(nb[0], dx, fmaf(nb[1], dy, nb[2] * dz));
    const float X1 = fmaf(nb[3], dx, fmaf(nb[4], dy, nb[5] * dz));
    const float X2 = fmaf(nb[6], dx, fmaf(nb[7], dy, nb[8] * dz));
    const float dn = fmaf(nb[0], nx, fmaf(nb[1], ny, nb[2] * nz));
    const float dd = fmaf(dx, dx, fmaf(dy, dy, dz * dz));
    const float tt = 2.f - dn;
    const float w = __expf(-dd * tt * tt);

    float hc[8];
#pragma unroll
    for (int cc = 0; cc < 8; ++cc)
      hc[cc] = w * fmaxf(fmaf(X0, a1v[cc * 3 + 0],
                         fmaf(X1, a1v[cc * 3 + 1],
                         fmaf(X2, a1v[cc * 3 + 2], b1v[cc]))), 0.f);
    float4 lo;
    lo.x = __builtin_bit_cast(float, pk16(hc[0], hc[1]));
    lo.y = __builtin_bit_cast(float, pk16(hc[2], hc[3]));
    lo.z = __builtin_bit_cast(float, pk16(hc[4], hc[5]));
    lo.w = __builtin_bit_cast(float, pk16(hc[6], hc[7]));
    // A-frag staging: tile jt = lane>>4, row m = l15
    hcA[wv][lane >> 4][l15] = lo;                       // kg0 (k 0..7)
    ((float*)&hcA[wv][lane >> 4][16 + l15])[0] =
        __builtin_bit_cast(float, pk16(w, 0.f));        // kg1 word0 (k8 = w)

    __syncthreads();                     // f_s + hcA visible

    // phase 2: 4 jt x 4 ht tiles
#pragma unroll
    for (int jt = 0; jt < 4; ++jt) {
      const float4* ap = (kg < 2) ? &hcA[wv][jt][kg * 16 + l15] : &zero4_s;
      const f16x8 af = __builtin_bit_cast(f16x8, *ap);
      const int fbase = (16 * jt + kg * 4) * FS_STRIDE + l15;
#pragma unroll
      for (int ht = 0; ht < 4; ++ht) {
        const f32x4 D = __builtin_amdgcn_mfma_f32_16x16x32_f16(
            af, bfrag[ht], kzero, 0, 0, 0);
        const float* fb = &f_s[fbase + 16 * ht];
#pragma unroll
        for (int r = 0; r < 4; ++r)
          acc[ht] = fmaf(fb[r * FS_STRIDE], fmaxf(D[r], 0.f), acc[ht]);
      }
    }
  }

  // each col's sum is spread over the 4 lane quads: reduce, lanes 0..15 store
#pragma unroll
  for (int ht = 0; ht < 4; ++ht) {
    acc[ht] += __shfl_xor(acc[ht], 16, 64);
    acc[ht] += __shfl_xor(acc[ht], 32, 64);
  }
  if (lane < 16) {
#pragma unroll
    for (int ht = 0; ht < 4; ++ht)
      cbuf[b * 64 + 16 * ht + lane] = acc[ht];
  }
}

extern "C" void kernel_launch(void* const* d_in, const int* in_sizes, int n_in,
                              void* d_out, int out_size, void* d_ws, size_t ws_size,
                              hipStream_t stream) {
  (void)in_sizes; (void)n_in; (void)out_size; (void)ws_size;
  const uint32_t* dref = (const uint32_t*)d_in[7];   // gn_in_w, all-ones

  float* pool   = (float*)d_ws;               // CVT_TOTAL fp32 inputs
  float* fbuf   = pool + CVT_TOTAL;           // N*64
  float* cbuf   = fbuf + N_PTS * 64;          // N*64
  float* gstats = cbuf + N_PTS * 64;          // 16 (in:0-7, out:8-15)

  InPtrs ptrs;
  for (int i = 0; i < NSEG; ++i) ptrs.p[i] = d_in[i];

  prep_kernel<<<256, 256, 0, stream>>>(ptrs, pool, gstats);
  mlp_in_kernel<<<N_PTS / 4, 256, 0, stream>>>(pool, fbuf);
  gn_stats_kernel<<<64, 256, 0, stream>>>(fbuf, gstats);
  gn_apply_kernel<<<N_PTS * 64 / 256, 256, 0, stream>>>(fbuf, gstats, pool);
  conv_kernel<<<N_PTS / WPB, 512, 0, stream>>>(pool, fbuf, cbuf);
  mlp_out_kernel<<<N_PTS / 4, 256, 0, stream>>>(cbuf, pool, fbuf);
  gn_stats_kernel<<<64, 256, 0, stream>>>(fbuf, gstats + 8);
  gn_apply_out_kernel<<<N_PTS * 64 / 256, 256, 0, stream>>>(
      fbuf, gstats + 8, pool, d_out, dref);
}